// Round 13
// baseline (234.917 us; speedup 1.0000x reference)
//
#include <hip/hip_runtime.h>

// LSTM: B=2048, T=512, I=6, H=50, O=3. fp32 in/out, bf16 MFMA inner matmul.
//
// R16 = R15's uniform B-addressing (proven: VALUBusy 46.7 -> 40.9%) with
// the x-feed copy DISTRIBUTED: lane 0 of wave w copies batch row w
// (Xpack[t+1] -> Aw[w][shorts 48..55]; 1 b128 read + 1 b128 write,
// wave-uniform address, ~10cy symmetric duty). R15 assigned the whole
// copy to wave 7 -> straggler: the barrier waits for the slowest wave,
// so its +60-100cy chain hit every step (153.6 -> 163.7 despite the
// issue cut landing). Barrier arithmetic: wall = max over waves, not sum.
//
// Ledger (cyc/step): R4 990 -> R5 860 -> R8 832 -> R9 750 -> R10 737 ->
// R11/R14 718 (153.6us best). Verdicts: 2 same-WG waves/SIMD optimal
// (R6/R7/R8); DS-count cut -2% (R10); VALU cut -2.6% (R11); setprio null
// (R12); indep-MFMA select-add negative (R13); asymmetric copy duty
// negative (R15); conflicts = one-time staging, off-path (R9/R10).
// NOT memory-bound (HBM 1%) nor compute-bound (Mfma 18%/VALU 47%).
//
// Structure: NB=8, 512 thr, 8 waves, 1 WG/CU. Abuf row: 0..47 h, 48..55
// x|bias (copied per step), 56..57 h48/49, 58..71 pad. k'-map: 0..47 =
// W_hh, 48..53 = W_ih, 54 = bias, 56..57 = W_hh cols 48..49. Broadcast-B
// (bb=col&7): every lane holds its (bb,hh) gate quad; tile select = 4
// cndmask. Fused 7-transcendental cell (5 exp2 + 2 rcp, med3 clamp),
// weights pre-scaled L2E / 2*L2E. AP=88 bank-spread. 1 barrier/step.

#define L2E 1.44269504088896340736f

typedef float  f32x4 __attribute__((ext_vector_type(4)));
typedef short  s16x8 __attribute__((ext_vector_type(8)));   // 8 bf16 bit-patterns

__device__ __forceinline__ float fast_exp2(float x){ return __builtin_amdgcn_exp2f(x); }
__device__ __forceinline__ float fast_rcp (float x){ return __builtin_amdgcn_rcpf(x); }

// float -> bf16 bits, round-to-nearest-even (weight staging only)
__device__ __forceinline__ unsigned short f2bf(float f){
  unsigned u = __builtin_bit_cast(unsigned, f);
  u = (u + 0x7FFFu + ((u >> 16) & 1u)) >> 16;
  return (unsigned short)u;
}

// single-instruction f32 -> bf16 (RNE) for the hot loop
__device__ __forceinline__ unsigned short f2bf_fast(float f){
  unsigned r;
  asm("v_cvt_pk_bf16_f32 %0, %1, %2" : "=v"(r) : "v"(f), "v"(0.0f));
  return (unsigned short)r;
}

// gates pre-scaled: g[0,1,3] = L2E*(i,f,o), g[2] = 2*L2E*g. Updates c,
// returns h. 7 transcendentals (5 exp2 + 2 rcp); med3 clamp on the chain.
__device__ __forceinline__ float lstm_cell(const f32x4 g, float& c){
  const float ef = fast_exp2(-g[1]);
  const float ei = fast_exp2(-g[0]);
  const float eg = fast_exp2(g[2]);          // |g2| <= ~33: no clamp needed
  const float A  = 1.0f + ef;
  const float Bq = 1.0f + ei;
  const float Cq = 1.0f + eg;
  const float BC = Bq * Cq;
  // c' = sig(f)*c + sig(i)*tanh(g) = (c*BC + (eg-1)*A) / (A*BC)
  const float num = fmaf(eg - 1.0f, A, c * BC);
  c = num * fast_rcp(A * BC);
  const float yc = __builtin_amdgcn_fmed3f(c * (2.0f * L2E), -115.f, 115.f);
  const float ec = fast_exp2(yc);
  const float eo = fast_exp2(-g[3]);
  const float r2 = fast_rcp((1.0f + eo) * (1.0f + ec));
  return (ec - 1.0f) * r2;                   // sig(o)*tanh(c)
}

constexpr int B_ = 2048, T_ = 512, I_ = 6, H_ = 50;
constexpr int NB = 8;       // batch rows per WG  (grid = 256 = 1 WG/CU)
constexpr int AP = 88;      // Abuf row pitch in bf16 elems (176 B: bank-spread)
constexpr int T6 = T_ * I_;

__global__ __launch_bounds__(512, 1)
void lstm_kernel(const float* __restrict__ x,
                 const float* __restrict__ W_ih, const float* __restrict__ W_hh,
                 const float* __restrict__ b_ih, const float* __restrict__ b_hh,
                 const float* __restrict__ W_out, const float* __restrict__ b_out,
                 float* __restrict__ out)
{
  // Xpack flat, XOR-swizzled: (t,b) slot = t*64 + (b*8 ^ ((t&7)<<3)) shorts.
  // Slot content = [x0..x5, bias=1.0, 0] = k' 48..55 of the B-operand.
  __shared__ unsigned short Xpack[T_ * NB * 8]; // 64 KB
  __shared__ unsigned short Abuf[2][NB * AP];   // 2.75 KB; row layout above
  __shared__ float Hlast[NB][H_];

  const int tid  = threadIdx.x;
  const int lane = tid & 63;
  const int wave = tid >> 6;     // 0..7
  const int col  = lane & 15;    // MFMA N index
  const int quad = lane >> 4;    // MFMA k-slice group
  const int bb   = col & 7;      // batch row (2-way broadcast)
  const bool lo  = col < 8;      // tile select: lo -> tile wave, hi -> wave+8
  const int b0   = blockIdx.x * NB;

  // ---- stage Xpack: thread tid handles t = tid (coalesced 24B reads) ----
  {
    const int tt = tid;          // 512 threads = 512 timesteps
    const int swz = (tt & 7) << 3;
    #pragma unroll
    for (int i = 0; i < NB; i++) {
      const float* xp = x + (size_t)(b0 + i) * T6 + tt * I_;
      const float2 a0 = *(const float2*)(xp);
      const float2 a1 = *(const float2*)(xp + 2);
      const float2 a2 = *(const float2*)(xp + 4);
      s16x8 w;
      w[0] = (short)f2bf(a0.x); w[1] = (short)f2bf(a0.y);
      w[2] = (short)f2bf(a1.x); w[3] = (short)f2bf(a1.y);
      w[4] = (short)f2bf(a2.x); w[5] = (short)f2bf(a2.y);
      w[6] = (short)0x3F80;     w[7] = 0;           // [bias=1.0, 0]
      *(s16x8*)&Xpack[tt * 64 + (i * 8 ^ swz)] = w;
    }
  }
  for (int i = tid; i < 2 * NB * AP; i += 512) (&Abuf[0][0])[i] = 0;

  // ---- weight fragments, pre-scaled, k'-map. Wave w: tiles jt = w + 8*ti.
  // jt >= 13 -> jp >= 208 -> zero tiles (uniform 2-tile loop, balanced).
  // k': 0..47 -> W_hh[.][k'], 48..53 -> W_ih[.][k'-48], 54 -> bias,
  //     56,57 -> W_hh[.][48,49], else 0.
  s16x8 wfh[2][2];
  #pragma unroll
  for (int ti = 0; ti < 2; ti++) {
    const int jp = (wave + 8 * ti) * 16 + col;
    const bool ok = jp < 200;
    const int hidx = jp >> 2, gat = jp & 3;
    const int row = gat * 50 + hidx;
    const float scl = (gat == 2) ? (2.0f * L2E) : L2E;
    #pragma unroll
    for (int kh = 0; kh < 2; kh++) {
      s16x8 w;
      #pragma unroll
      for (int kk = 0; kk < 8; kk++) {
        const int k = kh * 32 + quad * 8 + kk;
        float v = 0.0f;
        if (ok) {
          if      (k < 48)  v = W_hh[row * 50 + k];
          else if (k < 54)  v = W_ih[row * 6 + (k - 48)];
          else if (k == 54) v = b_ih[row] + b_hh[row];
          else if (k == 56) v = W_hh[row * 50 + 48];
          else if (k == 57) v = W_hh[row * 50 + 49];
        }
        w[kk] = (short)f2bf(v * scl);
      }
      wfh[ti][kh] = w;
    }
  }

  // ---- lane pair identity: tile jt = wave + 8*(col>=8), hh = 4*jt + quad ----
  const int jt_r = wave + 8 * (lo ? 0 : 1);
  const int hh   = 4 * jt_r + quad;
  const bool valid = (jt_r < 13) && (hh < H_);
  const int pos   = hh + ((hh >= 48) ? 8 : 0);   // h48,h49 at 56,57; invalid
                                                 // lanes land in pad 58..71

  float c_ = 0.f, hreg = 0.f;
  const f32x4 zz = {0.f, 0.f, 0.f, 0.f};

  __syncthreads();
  // seed x(0) into Abuf[0] shorts 48..55 (swz = 0 at t=0)
  if (tid < NB)
    *(s16x8*)&Abuf[0][tid * AP + 48] = *(const s16x8*)&Xpack[tid * 8];
  __syncthreads();

  #pragma unroll 8
  for (int t = 0; t < T_; t++) {
    const unsigned short* Ar = &Abuf[t & 1][0];
    unsigned short*       Aw = &Abuf[(t + 1) & 1][0];

    // x-feed for step t+1, DISTRIBUTED: lane 0 of wave w copies batch row
    // w's x-slice (wave-uniform address; ~10cy symmetric duty per wave).
    if (lane == 0) {
      const int tn = (t + 1) & (T_ - 1);
      *(s16x8*)&Aw[wave * AP + 48] =
          *(const s16x8*)&Xpack[tn * 64 + (wave * 8 ^ ((tn & 7) << 3))];
    }

    // B-frags, broadcast row (col&7): UNIFORM addresses for all lanes.
    const unsigned short* arow = Ar + bb * AP;
    const s16x8 bfr0 = *(const s16x8*)(arow + quad * 8);        // k' 0..31
    const s16x8 bfr1 = *(const s16x8*)(arow + 32 + quad * 8);   // k' 32..63

    // 2 MFMAs per tile (K=64 covers h + x + bias)
    f32x4 a[2];
    #pragma unroll
    for (int ti = 0; ti < 2; ti++) {
      a[ti] = __builtin_amdgcn_mfma_f32_16x16x32_bf16(wfh[ti][0], bfr0, zz,    0, 0, 0);
      a[ti] = __builtin_amdgcn_mfma_f32_16x16x32_bf16(wfh[ti][1], bfr1, a[ti], 0, 0, 0);
    }

    // tile select: every lane already holds its (bb, hh) quad
    f32x4 g;
    #pragma unroll
    for (int r = 0; r < 4; r++) g[r] = lo ? a[0][r] : a[1][r];

    hreg = lstm_cell(g, c_);
    Aw[bb * AP + pos] = f2bf_fast(hreg);   // unconditional: pad-safe

    __syncthreads();  // h + x-feed visible to all waves; lgkm-only drain
  }

  // ---- epilogue: logits + softmax ----
  if (valid) Hlast[bb][hh] = hreg;
  __syncthreads();

  if (tid < NB) {
    float l[3];
    #pragma unroll
    for (int o = 0; o < 3; o++) {
      float s = b_out[o];
      for (int k = 0; k < H_; k++) s += W_out[o * H_ + k] * Hlast[tid][k];
      l[o] = s;
    }
    const float m  = fmaxf(l[0], fmaxf(l[1], l[2]));
    const float e0 = fast_exp2((l[0] - m) * L2E);
    const float e1 = fast_exp2((l[1] - m) * L2E);
    const float e2 = fast_exp2((l[2] - m) * L2E);
    const float inv = fast_rcp(e0 + e1 + e2);
    float* op = out + (size_t)(b0 + tid) * 3;
    op[0] = e0 * inv; op[1] = e1 * inv; op[2] = e2 * inv;
  }
}

extern "C" void kernel_launch(void* const* d_in, const int* in_sizes, int n_in,
                              void* d_out, int out_size, void* d_ws, size_t ws_size,
                              hipStream_t stream) {
  const float* x     = (const float*)d_in[0];
  const float* W_ih  = (const float*)d_in[1];
  const float* W_hh  = (const float*)d_in[2];
  const float* b_ih  = (const float*)d_in[3];
  const float* b_hh  = (const float*)d_in[4];
  const float* W_out = (const float*)d_in[5];
  const float* b_out = (const float*)d_in[6];
  lstm_kernel<<<B_ / NB, 512, 0, stream>>>(x, W_ih, W_hh, b_ih, b_hh,
                                           W_out, b_out, (float*)d_out);
}

// Round 14
// 209.621 us; speedup vs baseline: 1.1207x; 1.1207x over previous
//
#include <hip/hip_runtime.h>

// LSTM: B=2048, T=512, I=6, H=50, O=3. fp32 in/out, bf16 MFMA inner matmul.
//
// R17 = FREEZE at R14 (measured 153.6us, session best; 2.1x vs the 322us
// session start). R15/R16 (x-in-Abuf copy schemes) both regressed: R15's
// single-wave copy made a barrier straggler (+10us); R16's distributed
// copy put a ds_read->waitcnt->ds_write stall at the top of EVERY wave's
// step (+34us, VALUBusy 47->37% while the wall rose — critical-path-bound,
// not issue-bound). Pre-committed stopping rule fired; this is the revert.
//
// Ledger (cyc/step): R4 990 -> R5 860 -> R8 832 -> R9 750 -> R10 737 ->
// R11/R14 718. Structural floor: barrier-synchronized recurrent exchange,
// 512 serial steps x (post-barrier ds_read latency + MFMA dep + 7-trans
// cell chain + write/drain/barrier). Measured verdicts: 2 same-WG
// waves/SIMD optimal (R6/R7/R8); DS-count cut -2% (R10); VALU cut -2.6%
// (R11); setprio null (R12); indep-MFMA select-add negative (R13); copy
// placement negative both ways (R15/R16); bank conflicts = one-time
// staging, off-path (R9/R10 byte-identical counter). NOT memory-bound
// (HBM 1%) nor compute-bound (MfmaUtil 18%, VALUBusy 47%).
//
// Structure: NB=8, 512 thr, 8 waves, 1 WG/CU. k'-map: 0..47 = W_hh cols
// 0..47, 48..53 = W_ih (x), 54 = bias, 56..57 = W_hh cols 48..49; quad2's
// bfr1 slice read straight from prepacked Xpack[t] (no per-step copy).
// Broadcast-B: bb = col&7 duplicates batch cols into 8..15 so every lane
// holds its (bb, hh) gate quad in the acc; tile select = 4 cndmask.
// Fused 7-transcendental cell (5 exp2 + 2 rcp, med3 clamp), weights
// pre-scaled by L2E / 2*L2E. AP=88 bank-spread. XOR-swizzled Xpack
// staging. 1 barrier/step, lgkm-only drain; c-state in registers.

#define L2E 1.44269504088896340736f

typedef float  f32x4 __attribute__((ext_vector_type(4)));
typedef short  s16x8 __attribute__((ext_vector_type(8)));   // 8 bf16 bit-patterns

__device__ __forceinline__ float fast_exp2(float x){ return __builtin_amdgcn_exp2f(x); }
__device__ __forceinline__ float fast_rcp (float x){ return __builtin_amdgcn_rcpf(x); }

// float -> bf16 bits, round-to-nearest-even (weight staging only)
__device__ __forceinline__ unsigned short f2bf(float f){
  unsigned u = __builtin_bit_cast(unsigned, f);
  u = (u + 0x7FFFu + ((u >> 16) & 1u)) >> 16;
  return (unsigned short)u;
}

// single-instruction f32 -> bf16 (RNE) for the hot loop
__device__ __forceinline__ unsigned short f2bf_fast(float f){
  unsigned r;
  asm("v_cvt_pk_bf16_f32 %0, %1, %2" : "=v"(r) : "v"(f), "v"(0.0f));
  return (unsigned short)r;
}

// gates pre-scaled: g[0,1,3] = L2E*(i,f,o), g[2] = 2*L2E*g. Updates c,
// returns h. 7 transcendentals (5 exp2 + 2 rcp); med3 clamp on the chain.
__device__ __forceinline__ float lstm_cell(const f32x4 g, float& c){
  const float ef = fast_exp2(-g[1]);
  const float ei = fast_exp2(-g[0]);
  const float eg = fast_exp2(g[2]);          // |g2| <= ~33: no clamp needed
  const float A  = 1.0f + ef;
  const float Bq = 1.0f + ei;
  const float Cq = 1.0f + eg;
  const float BC = Bq * Cq;
  // c' = sig(f)*c + sig(i)*tanh(g) = (c*BC + (eg-1)*A) / (A*BC)
  const float num = fmaf(eg - 1.0f, A, c * BC);
  c = num * fast_rcp(A * BC);
  const float yc = __builtin_amdgcn_fmed3f(c * (2.0f * L2E), -115.f, 115.f);
  const float ec = fast_exp2(yc);
  const float eo = fast_exp2(-g[3]);
  const float r2 = fast_rcp((1.0f + eo) * (1.0f + ec));
  return (ec - 1.0f) * r2;                   // sig(o)*tanh(c)
}

constexpr int B_ = 2048, T_ = 512, I_ = 6, H_ = 50;
constexpr int NB = 8;       // batch rows per WG  (grid = 256 = 1 WG/CU)
constexpr int AP = 88;      // Abuf row pitch in bf16 elems (176 B: bank-spread)
constexpr int T6 = T_ * I_;

__global__ __launch_bounds__(512, 1)
void lstm_kernel(const float* __restrict__ x,
                 const float* __restrict__ W_ih, const float* __restrict__ W_hh,
                 const float* __restrict__ b_ih, const float* __restrict__ b_hh,
                 const float* __restrict__ W_out, const float* __restrict__ b_out,
                 float* __restrict__ out)
{
  // Xpack flat, XOR-swizzled: (t,b) slot = t*64 + (b*8 ^ ((t&7)<<3)) shorts.
  // Slot content = [x0..x5, bias=1.0, 0] = k' 48..55 of the B-operand.
  __shared__ unsigned short Xpack[T_ * NB * 8]; // 64 KB
  __shared__ unsigned short Abuf[2][NB * AP];   // 2.75 KB: h at 0..47,56,57
  __shared__ float Hlast[NB][H_];

  const int tid  = threadIdx.x;
  const int lane = tid & 63;
  const int wave = tid >> 6;     // 0..7
  const int col  = lane & 15;    // MFMA N index
  const int quad = lane >> 4;    // MFMA k-slice group
  const int bb   = col & 7;      // batch row (2-way broadcast)
  const bool lo  = col < 8;      // tile select: lo -> tile wave, hi -> wave+8
  const int b0   = blockIdx.x * NB;

  // ---- stage Xpack: thread tid handles t = tid (coalesced 24B reads) ----
  {
    const int tt = tid;          // 512 threads = 512 timesteps
    const int swz = (tt & 7) << 3;
    #pragma unroll
    for (int i = 0; i < NB; i++) {
      const float* xp = x + (size_t)(b0 + i) * T6 + tt * I_;
      const float2 a0 = *(const float2*)(xp);
      const float2 a1 = *(const float2*)(xp + 2);
      const float2 a2 = *(const float2*)(xp + 4);
      s16x8 w;
      w[0] = (short)f2bf(a0.x); w[1] = (short)f2bf(a0.y);
      w[2] = (short)f2bf(a1.x); w[3] = (short)f2bf(a1.y);
      w[4] = (short)f2bf(a2.x); w[5] = (short)f2bf(a2.y);
      w[6] = (short)0x3F80;     w[7] = 0;           // [bias=1.0, 0]
      *(s16x8*)&Xpack[tt * 64 + (i * 8 ^ swz)] = w;
    }
  }
  for (int i = tid; i < 2 * NB * AP; i += 512) (&Abuf[0][0])[i] = 0;

  // ---- weight fragments, pre-scaled, k'-map. Wave w: tiles jt = w + 8*ti.
  // jt >= 13 -> jp >= 208 -> zero tiles (uniform 2-tile loop, balanced).
  // k': 0..47 -> W_hh[.][k'], 48..53 -> W_ih[.][k'-48], 54 -> bias,
  //     56,57 -> W_hh[.][48,49], else 0.
  s16x8 wfh[2][2];
  #pragma unroll
  for (int ti = 0; ti < 2; ti++) {
    const int jp = (wave + 8 * ti) * 16 + col;
    const bool ok = jp < 200;
    const int hidx = jp >> 2, gat = jp & 3;
    const int row = gat * 50 + hidx;
    const float scl = (gat == 2) ? (2.0f * L2E) : L2E;
    #pragma unroll
    for (int kh = 0; kh < 2; kh++) {
      s16x8 w;
      #pragma unroll
      for (int kk = 0; kk < 8; kk++) {
        const int k = kh * 32 + quad * 8 + kk;
        float v = 0.0f;
        if (ok) {
          if      (k < 48)  v = W_hh[row * 50 + k];
          else if (k < 54)  v = W_ih[row * 6 + (k - 48)];
          else if (k == 54) v = b_ih[row] + b_hh[row];
          else if (k == 56) v = W_hh[row * 50 + 48];
          else if (k == 57) v = W_hh[row * 50 + 49];
        }
        w[kk] = (short)f2bf(v * scl);
      }
      wfh[ti][kh] = w;
    }
  }

  // ---- lane pair identity: tile jt = wave + 8*(col>=8), hh = 4*jt + quad ----
  const int jt_r = wave + 8 * (lo ? 0 : 1);
  const int hh   = 4 * jt_r + quad;
  const bool valid = (jt_r < 13) && (hh < H_);
  const int pos   = hh + ((hh >= 48) ? 8 : 0);   // h48,h49 at 56,57; invalid
                                                 // lanes land in pad 58..71

  float c_ = 0.f, hreg = 0.f;
  const f32x4 zz = {0.f, 0.f, 0.f, 0.f};

  __syncthreads();

  #pragma unroll 8
  for (int t = 0; t < T_; t++) {
    const unsigned short* Ar = &Abuf[t & 1][0];
    unsigned short*       Aw = &Abuf[(t + 1) & 1][0];

    // B-frags, broadcast row (col&7). quad2's bfr1 slice (k' 48..55) is
    // [x|bias|0], read straight from Xpack via per-lane address select.
    const unsigned short* arow = Ar + bb * AP;
    const s16x8 bfr0 = *(const s16x8*)(arow + quad * 8);        // k' 0..31
    const unsigned short* p1 = (quad == 2)
        ? &Xpack[t * 64 + (bb * 8 ^ ((t & 7) << 3))]
        : (arow + 32 + quad * 8);
    const s16x8 bfr1 = *(const s16x8*)p1;                       // k' 32..63

    // 2 MFMAs per tile (K=64 covers h + x + bias)
    f32x4 a[2];
    #pragma unroll
    for (int ti = 0; ti < 2; ti++) {
      a[ti] = __builtin_amdgcn_mfma_f32_16x16x32_bf16(wfh[ti][0], bfr0, zz,    0, 0, 0);
      a[ti] = __builtin_amdgcn_mfma_f32_16x16x32_bf16(wfh[ti][1], bfr1, a[ti], 0, 0, 0);
    }

    // tile select: every lane already holds its (bb, hh) quad
    f32x4 g;
    #pragma unroll
    for (int r = 0; r < 4; r++) g[r] = lo ? a[0][r] : a[1][r];

    hreg = lstm_cell(g, c_);
    Aw[bb * AP + pos] = f2bf_fast(hreg);   // unconditional: pad-safe

    __syncthreads();  // h visible to all waves; lgkm-only drain (no vmcnt)
  }

  // ---- epilogue: logits + softmax ----
  if (valid) Hlast[bb][hh] = hreg;
  __syncthreads();

  if (tid < NB) {
    float l[3];
    #pragma unroll
    for (int o = 0; o < 3; o++) {
      float s = b_out[o];
      for (int k = 0; k < H_; k++) s += W_out[o * H_ + k] * Hlast[tid][k];
      l[o] = s;
    }
    const float m  = fmaxf(l[0], fmaxf(l[1], l[2]));
    const float e0 = fast_exp2((l[0] - m) * L2E);
    const float e1 = fast_exp2((l[1] - m) * L2E);
    const float e2 = fast_exp2((l[2] - m) * L2E);
    const float inv = fast_rcp(e0 + e1 + e2);
    float* op = out + (size_t)(b0 + tid) * 3;
    op[0] = e0 * inv; op[1] = e1 * inv; op[2] = e2 * inv;
  }
}

extern "C" void kernel_launch(void* const* d_in, const int* in_sizes, int n_in,
                              void* d_out, int out_size, void* d_ws, size_t ws_size,
                              hipStream_t stream) {
  const float* x     = (const float*)d_in[0];
  const float* W_ih  = (const float*)d_in[1];
  const float* W_hh  = (const float*)d_in[2];
  const float* b_ih  = (const float*)d_in[3];
  const float* b_hh  = (const float*)d_in[4];
  const float* W_out = (const float*)d_in[5];
  const float* b_out = (const float*)d_in[6];
  lstm_kernel<<<B_ / NB, 512, 0, stream>>>(x, W_ih, W_hh, b_ih, b_hh,
                                           W_out, b_out, (float*)d_out);
}